// Round 15
// baseline (309.983 us; speedup 1.0000x reference)
//
#include <hip/hip_runtime.h>
#include <hip/hip_bf16.h>

#define B_ 256
#define T_ 400
#define NMELS 80
#define INP 512
#define DEC_ 128
#define LSTM_ 1024
#define FILT 32
#define KS 31
#define MAXR 20
#define TCH 2

typedef float f32x4 __attribute__((ext_vector_type(4)));
typedef short bf16x8 __attribute__((ext_vector_type(8)));

__device__ __forceinline__ short f2bf(float f) {
  union { float f; unsigned u; } v; v.f = f;
  unsigned u = v.u;
  unsigned r = (u + 0x7fffu + ((u >> 16) & 1u)) >> 16;
  return (short)r;
}

__device__ __forceinline__ bf16x8 pack8(float4 a0, float4 a1) {
  bf16x8 r;
  r[0] = f2bf(a0.x); r[1] = f2bf(a0.y); r[2] = f2bf(a0.z); r[3] = f2bf(a0.w);
  r[4] = f2bf(a1.x); r[5] = f2bf(a1.y); r[6] = f2bf(a1.z); r[7] = f2bf(a1.w);
  return r;
}

__device__ __forceinline__ float sigmoidf_(float x) {
  return 1.f / (1.f + __expf(-x));
}
__device__ __forceinline__ float tanhf_(float x) {
  float e = __expf(2.f * x);
  return 1.f - 2.f / (e + 1.f);
}

// ---------------------------------------------------------------------------
struct Args {
  const float *enc, *esp, *prein, *ah0, *h1_0, *h2_0, *c1_0, *c2_0, *ctx0, *cum;
  const int* chars;
  const float *pw1, *pb1, *pw2, *pb2;
  const float *gwih, *gwhh, *gbih, *gbhh;
  const float *cvw, *cvb, *lsaL, *lsaW, *lsaWb, *lsav;
  const float *riw, *rib;
  const float *l1wih, *l1whh, *l1bih, *l1bhh;
  const float *l2wih, *l2whh, *l2bih, *l2bhh;
  const float *melw, *stopw, *stopb;
  float *o_mels, *o_scores, *o_attn, *o_h1, *o_h2, *o_c1, *o_c2, *o_ctx, *o_stop, *o_cum;
  float *ws_u, *ws_part, *ws_x, *ws_x2, *ws_g4;
};

// ---------------------------------------------------------------------------
// Fused head + attention scores. Grid (2, B). Each block redundantly computes
// the prenet/GRU head for its b (pq stays in LDS), then MFMA scores for its
// 200-t half. half==0 block also writes o_attn (new GRU hidden).
// ---------------------------------------------------------------------------
struct HeadOv {          // head-phase scratch (overlays conv region)
  float s_p[80];
  float s_hold[DEC_];
  float s_h1[256];
  float s_x[768];
  float s_gi[384];
  float s_gh[384];
};
struct ConvOv {          // conv/MFMA-phase scratch
  short s_conv[208][40];
  short s_L[128][40];
};

__global__ __launch_bounds__(256) void attn_fused_kernel(Args a) {
  __shared__ float s_cum[232];
  __shared__ float s_w[FILT * KS];
  __shared__ float s_cb[FILT];
  __shared__ float s_pq[DEC_];
  __shared__ float s_v[DEC_];
  __shared__ __align__(16) char ovl[sizeof(ConvOv)];
  HeadOv* H = (HeadOv*)ovl;
  ConvOv* C = (ConvOv*)ovl;

  const int half = blockIdx.x;
  const int b    = blockIdx.y;
  const int tid  = threadIdx.x;
  const int t0   = half * 200;

  // --- stage persistent small arrays + head inputs -------------------------
  for (int i = tid; i < 230; i += 256) {
    int t = t0 - 15 + i;
    s_cum[i] = (t >= 0 && t < T_) ? a.cum[(size_t)b * T_ + t] : 0.f;
  }
  for (int i = tid; i < FILT * KS; i += 256) s_w[i] = a.cvw[i];
  if (tid < FILT) s_cb[tid] = a.cvb[tid];
  if (tid < DEC_) s_v[tid] = a.lsav[tid];
  if (tid < 80)   H->s_p[tid]    = a.prein[(size_t)b * 80 + tid];
  if (tid >= 128 && tid < 256) H->s_hold[tid - 128] = a.ah0[(size_t)b * DEC_ + tid - 128];
  for (int i = tid; i < INP; i += 256) H->s_x[i] = a.ctx0[(size_t)b * INP + i];
  __syncthreads();

  // --- head: prenet1 -------------------------------------------------------
  {
    const float* w = a.pw1 + (size_t)tid * 80;
    float acc = a.pb1[tid];
#pragma unroll
    for (int k = 0; k < 80; k += 4)
      acc += w[k] * H->s_p[k] + w[k+1] * H->s_p[k+1] + w[k+2] * H->s_p[k+2] + w[k+3] * H->s_p[k+3];
    H->s_h1[tid] = fmaxf(acc, 0.f);
  }
  __syncthreads();
  // --- prenet2 -------------------------------------------------------------
  {
    const float4* w = (const float4*)(a.pw2 + (size_t)tid * 256);
    float acc = a.pb2[tid];
#pragma unroll 8
    for (int q = 0; q < 64; ++q) {
      float4 wv = w[q];
      acc += wv.x * H->s_h1[q*4] + wv.y * H->s_h1[q*4+1] + wv.z * H->s_h1[q*4+2] + wv.w * H->s_h1[q*4+3];
    }
    H->s_x[INP + tid] = fmaxf(acc, 0.f);
  }
  __syncthreads();
  // --- gi / gh -------------------------------------------------------------
  for (int n = tid; n < 384; n += 256) {
    const float4* w = (const float4*)(a.gwih + (size_t)n * 768);
    float acc = a.gbih[n];
#pragma unroll 8
    for (int q = 0; q < 192; ++q) {
      float4 wv = w[q];
      acc += wv.x * H->s_x[q*4] + wv.y * H->s_x[q*4+1] + wv.z * H->s_x[q*4+2] + wv.w * H->s_x[q*4+3];
    }
    H->s_gi[n] = acc;
  }
  for (int n = tid; n < 384; n += 256) {
    const float4* w = (const float4*)(a.gwhh + (size_t)n * DEC_);
    float acc = a.gbhh[n];
#pragma unroll
    for (int q = 0; q < 32; ++q) {
      float4 wv = w[q];
      acc += wv.x * H->s_hold[q*4] + wv.y * H->s_hold[q*4+1] + wv.z * H->s_hold[q*4+2] + wv.w * H->s_hold[q*4+3];
    }
    H->s_gh[n] = acc;
  }
  __syncthreads();
  // --- GRU cell: h2 into s_gi[0..127] (s_gi free after this read) ----------
  if (tid < DEC_) {
    float r = sigmoidf_(H->s_gi[tid] + H->s_gh[tid]);
    float z = sigmoidf_(H->s_gi[128 + tid] + H->s_gh[128 + tid]);
    float n = tanhf_(H->s_gi[256 + tid] + r * H->s_gh[256 + tid]);
    float h = (1.f - z) * n + z * H->s_hold[tid];
    H->s_hold[tid] = h;                      // reuse s_hold for h_new
    if (half == 0) a.o_attn[(size_t)b * DEC_ + tid] = h;
  }
  __syncthreads();
  // --- processed_query -> s_pq (persists past overlay reuse) ---------------
  if (tid < DEC_) {
    const float4* w = (const float4*)(a.lsaW + (size_t)tid * DEC_);
    float acc = a.lsaWb[tid];
#pragma unroll
    for (int q = 0; q < 32; ++q) {
      float4 wv = w[q];
      acc += wv.x * H->s_hold[q*4] + wv.y * H->s_hold[q*4+1] + wv.z * H->s_hold[q*4+2] + wv.w * H->s_hold[q*4+3];
    }
    s_pq[tid] = acc;
  }
  __syncthreads();   // head phase done; overlay now reusable as ConvOv

  // --- conv + L staging ----------------------------------------------------
  for (int i = tid; i < DEC_ * FILT; i += 256) C->s_L[i >> 5][i & 31] = f2bf(a.lsaL[i]);
  C->s_conv[200 + (tid >> 5)][tid & 31] = 0;
  __syncthreads();   // ensure all head reads done before conv writes? (s_conv
                     // overlaps s_p/s_hold/s_h1 which are dead now)

  if (tid < 200) {
    float c[KS];
#pragma unroll
    for (int k = 0; k < KS; ++k) c[k] = s_cum[tid + k];
#pragma unroll
    for (int f = 0; f < FILT; ++f) {
      float acc = s_cb[f];
#pragma unroll
      for (int k = 0; k < KS; ++k) acc += c[k] * s_w[f * KS + k];
      C->s_conv[tid][f] = f2bf(acc);
    }
  }
  __syncthreads();

  // --- MFMA scores + tanh/v epilogue ---------------------------------------
  const int lane = tid & 63, wave = tid >> 6;
  const int l15 = lane & 15, kq = (lane >> 4) * 8;
  for (int m = wave; m < 13; m += 4) {
    bf16x8 af = *(const bf16x8*)&C->s_conv[m * 16 + l15][kq];
    f32x4 acc[8];
#pragma unroll
    for (int n = 0; n < 8; ++n) {
      bf16x8 bf = *(const bf16x8*)&C->s_L[n * 16 + l15][kq];
      acc[n] = __builtin_amdgcn_mfma_f32_16x16x32_bf16(af, bf, (f32x4){0.f, 0.f, 0.f, 0.f}, 0, 0, 0);
    }
    const int trow = m * 16 + (lane >> 4) * 4;
    float u[4] = {0.f, 0.f, 0.f, 0.f};
#pragma unroll
    for (int n = 0; n < 8; ++n) {
      int d = n * 16 + l15;
      float pqd = s_pq[d], vd = s_v[d];
#pragma unroll
      for (int r = 0; r < 4; ++r) {
        int tl = trow + r;
        if (tl < 200) {
          float x = acc[n][r] + pqd + a.esp[((size_t)b * T_ + t0 + tl) * DEC_ + d];
          u[r] += tanhf_(x) * vd;
        }
      }
    }
#pragma unroll
    for (int r = 0; r < 4; ++r) {
#pragma unroll
      for (int o = 1; o < 16; o <<= 1) u[r] += __shfl_xor(u[r], o);
    }
    if (l15 == 0) {
#pragma unroll
      for (int r = 0; r < 4; ++r) {
        int tl = trow + r;
        if (tl < 200) {
          int t = t0 + tl;
          float uu = u[r];
          if (a.chars[(size_t)b * T_ + t] == 0) uu = 0.f;
          a.ws_u[(size_t)b * T_ + t] = uu;
        }
      }
    }
  }
}

// ---------------------------------------------------------------------------
// Softmax (redundant per tc) + context partial over 200-t chunk. Block (tc,b).
// ---------------------------------------------------------------------------
__global__ __launch_bounds__(256) void ctx_smax_part_kernel(Args a) {
  __shared__ float s_u[T_];
  __shared__ float s_red[8];
  const int tc = blockIdx.x, b = blockIdx.y, tid = threadIdx.x;
  const int lane = tid & 63, wave = tid >> 6;

  float mx = -1e30f;
  for (int t = tid; t < T_; t += 256) {
    float v = a.ws_u[(size_t)b * T_ + t];
    s_u[t] = v;
    mx = fmaxf(mx, v);
  }
#pragma unroll
  for (int o = 32; o >= 1; o >>= 1) mx = fmaxf(mx, __shfl_xor(mx, o));
  if (lane == 0) s_red[wave] = mx;
  __syncthreads();
  mx = fmaxf(fmaxf(s_red[0], s_red[1]), fmaxf(s_red[2], s_red[3]));

  float smv = 0.f;
  for (int t = tid; t < T_; t += 256) {
    float e = __expf(s_u[t] - mx);
    s_u[t] = e;
    smv += e;
  }
#pragma unroll
  for (int o = 32; o >= 1; o >>= 1) smv += __shfl_xor(smv, o);
  if (lane == 0) s_red[4 + wave] = smv;
  __syncthreads();
  smv = s_red[4] + s_red[5] + s_red[6] + s_red[7];
  float inv = 1.f / smv;
  for (int t = tid; t < T_; t += 256) {
    float s = s_u[t] * inv;
    s_u[t] = s;
    if (tc == 0) {
      a.o_scores[(size_t)b * T_ + t] = s;
      a.o_cum[(size_t)b * T_ + t] = a.cum[(size_t)b * T_ + t] + s;
    }
  }
  __syncthreads();

  const int start = tc * 200;
  const float2* Eb = (const float2*)(a.enc + ((size_t)b * T_ + start) * INP) + tid;
  const float* su = &s_u[start];
  float2 a0 = {0.f, 0.f}, a1 = {0.f, 0.f}, a2 = {0.f, 0.f}, a3 = {0.f, 0.f};
  for (int t = 0; t < 200; t += 4) {
    float s0 = su[t], s1 = su[t + 1], s2 = su[t + 2], s3 = su[t + 3];
    float2 e0 = Eb[(size_t)(t)     * 256];
    float2 e1 = Eb[(size_t)(t + 1) * 256];
    float2 e2 = Eb[(size_t)(t + 2) * 256];
    float2 e3 = Eb[(size_t)(t + 3) * 256];
    a0.x += s0 * e0.x; a0.y += s0 * e0.y;
    a1.x += s1 * e1.x; a1.y += s1 * e1.y;
    a2.x += s2 * e2.x; a2.y += s2 * e2.y;
    a3.x += s3 * e3.x; a3.y += s3 * e3.y;
  }
  float2 r;
  r.x = (a0.x + a1.x) + (a2.x + a3.x);
  r.y = (a0.y + a1.y) + (a2.y + a3.y);
  *(float2*)&a.ws_part[((size_t)tc * B_ + b) * INP + 2 * tid] = r;
}

// ---------------------------------------------------------------------------
// Generic bf16-MFMA GEMM + optional A1-partial-sum staging (R13/R14-proven).
// ---------------------------------------------------------------------------
__global__ __launch_bounds__(256) void gemm_bf16(
    const float* __restrict__ A1, const float* __restrict__ A1b,
    float* __restrict__ ctx_side, int lda1,
    const float* __restrict__ W1, int ldw1, int K1,
    const float* __restrict__ A2, int lda2, const float* __restrict__ W2, int ldw2, int K2,
    const float* __restrict__ bias1, const float* __restrict__ bias2,
    float* __restrict__ out, int ldo, int act, int zmode)
{
  __shared__ __align__(16) short sA[64][40];
  __shared__ __align__(16) short sB[64][40];
  const int tid  = threadIdx.x;
  const int lane = tid & 63;
  const int wave = tid >> 6;
  const int wr = (wave >> 1) * 32;
  const int wc = (wave & 1) * 32;
  const int bm = blockIdx.y * 64;
  const int bn = blockIdx.x * 64;
  const int sr = tid >> 2;
  const int sk = (tid & 3) * 8;
  const int l15 = lane & 15;
  const int kq  = (lane >> 4) * 8;

  int kb1 = 0, ke1 = K1, kb2 = 0, ke2 = K2;
  if (zmode == 2) {
    int p = blockIdx.z >> 1, h = blockIdx.z & 1;
    if (p == 0) { ke2 = 0; int half = K1 >> 1; kb1 = h * half; ke1 = kb1 + half; }
    else        { ke1 = 0; int half = K2 >> 1; kb2 = h * half; ke2 = kb2 + half; }
  }
  float* outp = out;
  if (zmode == 2) outp += (size_t)blockIdx.z * (size_t)(gridDim.y * 64) * ldo;

  f32x4 acc[2][2];
#pragma unroll
  for (int i = 0; i < 2; ++i)
#pragma unroll
    for (int j = 0; j < 2; ++j) acc[i][j] = (f32x4){0.f, 0.f, 0.f, 0.f};

  for (int pair = 0; pair < 2; ++pair) {
    const int kb = pair ? kb2 : kb1;
    const int ke = pair ? ke2 : ke1;
    if (ke <= kb) continue;
    const float* A = pair ? A2 : A1;
    const float* Ab = pair ? nullptr : A1b;
    const float* W = pair ? W2 : W1;
    const int lda = pair ? lda2 : lda1;
    const int ldw = pair ? ldw2 : ldw1;
    const float* arow  = A + (size_t)(bm + sr) * lda;
    const float* arowb = Ab ? Ab + (size_t)(bm + sr) * lda : nullptr;
    const float* wrow  = W + (size_t)(bn + sr) * ldw;
    float* crow = (pair == 0 && ctx_side) ? ctx_side + (size_t)(bm + sr) * lda : nullptr;

    float4 ra0, ra1, rb0, rb1;
    if (kb + 32 <= ke) {
      const float* pa = arow + kb + sk;
      const float* pw = wrow + kb + sk;
      ra0 = *(const float4*)pa; ra1 = *(const float4*)(pa + 4);
      if (arowb) {
        const float* pb = arowb + kb + sk;
        float4 b0 = *(const float4*)pb, b1 = *(const float4*)(pb + 4);
        ra0.x += b0.x; ra0.y += b0.y; ra0.z += b0.z; ra0.w += b0.w;
        ra1.x += b1.x; ra1.y += b1.y; ra1.z += b1.z; ra1.w += b1.w;
      }
      rb0 = *(const float4*)pw; rb1 = *(const float4*)(pw + 4);
    }
    for (int k0 = kb; k0 < ke; k0 += 32) {
      __syncthreads();
      if (k0 + 32 <= ke) {
        *(bf16x8*)&sA[sr][sk] = pack8(ra0, ra1);
        *(bf16x8*)&sB[sr][sk] = pack8(rb0, rb1);
        if (crow) {
          *(float4*)(crow + k0 + sk) = ra0;
          *(float4*)(crow + k0 + sk + 4) = ra1;
        }
        if (k0 + 64 <= ke) {
          const float* pa = arow + k0 + 32 + sk;
          const float* pw = wrow + k0 + 32 + sk;
          ra0 = *(const float4*)pa; ra1 = *(const float4*)(pa + 4);
          if (arowb) {
            const float* pb = arowb + k0 + 32 + sk;
            float4 b0 = *(const float4*)pb, b1 = *(const float4*)(pb + 4);
            ra0.x += b0.x; ra0.y += b0.y; ra0.z += b0.z; ra0.w += b0.w;
            ra1.x += b1.x; ra1.y += b1.y; ra1.z += b1.z; ra1.w += b1.w;
          }
          rb0 = *(const float4*)pw; rb1 = *(const float4*)(pw + 4);
        }
      } else {
        short* da = &sA[sr][sk];
        short* db = &sB[sr][sk];
#pragma unroll
        for (int j = 0; j < 8; ++j) {
          int k = k0 + sk + j;
          float av = (k < ke) ? arow[k] + (arowb ? arowb[k] : 0.f) : 0.f;
          da[j] = (k < ke) ? f2bf(av) : (short)0;
          db[j] = (k < ke) ? f2bf(wrow[k]) : (short)0;
        }
      }
      __syncthreads();
      bf16x8 af[2], bfv[2];
      af[0]  = *(const bf16x8*)&sA[wr + l15][kq];
      af[1]  = *(const bf16x8*)&sA[wr + 16 + l15][kq];
      bfv[0] = *(const bf16x8*)&sB[wc + l15][kq];
      bfv[1] = *(const bf16x8*)&sB[wc + 16 + l15][kq];
#pragma unroll
      for (int i = 0; i < 2; ++i)
#pragma unroll
        for (int j = 0; j < 2; ++j)
          acc[i][j] = __builtin_amdgcn_mfma_f32_16x16x32_bf16(af[i], bfv[j], acc[i][j], 0, 0, 0);
    }
  }

#pragma unroll
  for (int i = 0; i < 2; ++i) {
#pragma unroll
    for (int j = 0; j < 2; ++j) {
      int n = bn + wc + j * 16 + l15;
      float bv = 0.f;
      if (zmode == 0) bv = (bias1 ? bias1[n] : 0.f) + (bias2 ? bias2[n] : 0.f);
#pragma unroll
      for (int r = 0; r < 4; ++r) {
        int m = bm + wr + i * 16 + (lane >> 4) * 4 + r;
        float v = acc[i][j][r] + bv;
        if (act == 1) v = fmaxf(v, 0.f);
        outp[(size_t)m * ldo + n] = v;
      }
    }
  }
}

// ---------------------------------------------------------------------------
// LSTM cell (4 gate partials) + residual (proven).
// ---------------------------------------------------------------------------
__global__ __launch_bounds__(256) void lstm_cell_kernel(
    const float* __restrict__ g4, const float* __restrict__ bih,
    const float* __restrict__ bhh, const float* __restrict__ c_old,
    const float* __restrict__ x_in,
    float* __restrict__ h_out, float* __restrict__ c_out,
    float* __restrict__ x_out)
{
  const size_t SEG = (size_t)B_ * 4096;
  int idx = blockIdx.x * 256 + threadIdx.x;
  if (idx >= B_ * LSTM_) return;
  int b = idx >> 10, j = idx & 1023;
  const float* gb = g4 + (size_t)b * 4096;
  float ig = gb[j]        + gb[SEG + j]        + gb[2*SEG + j]        + gb[3*SEG + j]        + bih[j]        + bhh[j];
  float fg = gb[1024 + j] + gb[SEG + 1024 + j] + gb[2*SEG + 1024 + j] + gb[3*SEG + 1024 + j] + bih[1024 + j] + bhh[1024 + j];
  float gg = gb[2048 + j] + gb[SEG + 2048 + j] + gb[2*SEG + 2048 + j] + gb[3*SEG + 2048 + j] + bih[2048 + j] + bhh[2048 + j];
  float og = gb[3072 + j] + gb[SEG + 3072 + j] + gb[2*SEG + 3072 + j] + gb[3*SEG + 3072 + j] + bih[3072 + j] + bhh[3072 + j];
  float cn = sigmoidf_(fg) * c_old[idx] + sigmoidf_(ig) * tanhf_(gg);
  float hn = sigmoidf_(og) * tanhf_(cn);
  h_out[idx] = hn;
  c_out[idx] = cn;
  x_out[idx] = x_in[idx] + hn;
}

// ---------------------------------------------------------------------------
// Fused cell2 + mel + stop. Grid (4, b). Each part redundantly computes the
// full cell2 row (x3 stays in LDS); part 0 writes h2/c2 and the stop token.
// Mel: 5 rows/wave, float4 loads, concurrent accumulators.
// ---------------------------------------------------------------------------
__global__ __launch_bounds__(256) void mel_cell_kernel(Args a) {
  __shared__ float s_x[LSTM_];
  __shared__ float s_c[INP];
  __shared__ float s_red[4];
  const int part = blockIdx.x;       // 0..3
  const int b    = blockIdx.y;
  const int tid  = threadIdx.x;
  const int lane = tid & 63, wave = tid >> 6;
  const size_t SEG = (size_t)B_ * 4096;

  // cell2 (all 1024 j per block; redundant across parts)
  const float* gb = a.ws_g4 + (size_t)b * 4096;
  for (int j = tid; j < LSTM_; j += 256) {
    float ig = gb[j]        + gb[SEG + j]        + gb[2*SEG + j]        + gb[3*SEG + j]        + a.l2bih[j]        + a.l2bhh[j];
    float fg = gb[1024 + j] + gb[SEG + 1024 + j] + gb[2*SEG + 1024 + j] + gb[3*SEG + 1024 + j] + a.l2bih[1024 + j] + a.l2bhh[1024 + j];
    float gg = gb[2048 + j] + gb[SEG + 2048 + j] + gb[2*SEG + 2048 + j] + gb[3*SEG + 2048 + j] + a.l2bih[2048 + j] + a.l2bhh[2048 + j];
    float og = gb[3072 + j] + gb[SEG + 3072 + j] + gb[2*SEG + 3072 + j] + gb[3*SEG + 3072 + j] + a.l2bih[3072 + j] + a.l2bhh[3072 + j];
    size_t idx = (size_t)b * LSTM_ + j;
    float cn = sigmoidf_(fg) * a.c2_0[idx] + sigmoidf_(ig) * tanhf_(gg);
    float hn = sigmoidf_(og) * tanhf_(cn);
    if (part == 0) { a.o_h2[idx] = hn; a.o_c2[idx] = cn; }
    s_x[j] = a.ws_x2[idx] + hn;
  }
  if (part == 0)
    for (int k = tid; k < INP; k += 256) s_c[k] = a.o_ctx[(size_t)b * INP + k];
  __syncthreads();

  const int n0 = part * 20 + wave * 5;
  const float* w0 = a.melw + (size_t)(n0)     * MAXR * LSTM_;
  const float* w1 = a.melw + (size_t)(n0 + 1) * MAXR * LSTM_;
  const float* w2 = a.melw + (size_t)(n0 + 2) * MAXR * LSTM_;
  const float* w3 = a.melw + (size_t)(n0 + 3) * MAXR * LSTM_;
  const float* w4 = a.melw + (size_t)(n0 + 4) * MAXR * LSTM_;
  float ac0 = 0.f, ac1 = 0.f, ac2 = 0.f, ac3 = 0.f, ac4 = 0.f;
#pragma unroll
  for (int j = 0; j < 4; ++j) {
    int k = j * 256 + lane * 4;
    float4 xv = *(const float4*)&s_x[k];
    float4 v0 = *(const float4*)(w0 + k);
    float4 v1 = *(const float4*)(w1 + k);
    float4 v2 = *(const float4*)(w2 + k);
    float4 v3 = *(const float4*)(w3 + k);
    float4 v4 = *(const float4*)(w4 + k);
    ac0 += v0.x * xv.x + v0.y * xv.y + v0.z * xv.z + v0.w * xv.w;
    ac1 += v1.x * xv.x + v1.y * xv.y + v1.z * xv.z + v1.w * xv.w;
    ac2 += v2.x * xv.x + v2.y * xv.y + v2.z * xv.z + v2.w * xv.w;
    ac3 += v3.x * xv.x + v3.y * xv.y + v3.z * xv.z + v3.w * xv.w;
    ac4 += v4.x * xv.x + v4.y * xv.y + v4.z * xv.z + v4.w * xv.w;
  }
#pragma unroll
  for (int o = 32; o >= 1; o >>= 1) {
    ac0 += __shfl_xor(ac0, o);
    ac1 += __shfl_xor(ac1, o);
    ac2 += __shfl_xor(ac2, o);
    ac3 += __shfl_xor(ac3, o);
    ac4 += __shfl_xor(ac4, o);
  }
  if (lane == 0) {
    float* om = a.o_mels + (size_t)b * NMELS + n0;
    om[0] = ac0; om[1] = ac1; om[2] = ac2; om[3] = ac3; om[4] = ac4;
  }

  if (part == 0) {
    float p = 0.f;
    for (int k = tid; k < LSTM_; k += 256) p += s_x[k] * a.stopw[k];
    for (int k = tid; k < INP; k += 256) p += s_c[k] * a.stopw[LSTM_ + k];
#pragma unroll
    for (int o = 32; o >= 1; o >>= 1) p += __shfl_xor(p, o);
    if (lane == 0) s_red[wave] = p;
    __syncthreads();
    if (tid == 0) {
      float t = s_red[0] + s_red[1] + s_red[2] + s_red[3] + a.stopb[0];
      a.o_stop[b] = sigmoidf_(t);
    }
  }
}

// ---------------------------------------------------------------------------
extern "C" void kernel_launch(void* const* d_in, const int* in_sizes, int n_in,
                              void* d_out, int out_size, void* d_ws, size_t ws_size,
                              hipStream_t stream) {
  Args a;
  a.enc   = (const float*)d_in[0];
  a.esp   = (const float*)d_in[1];
  a.prein = (const float*)d_in[2];
  a.ah0   = (const float*)d_in[3];
  a.h1_0  = (const float*)d_in[4];
  a.h2_0  = (const float*)d_in[5];
  a.c1_0  = (const float*)d_in[6];
  a.c2_0  = (const float*)d_in[7];
  a.ctx0  = (const float*)d_in[8];
  a.cum   = (const float*)d_in[9];
  a.chars = (const int*)d_in[10];
  a.pw1 = (const float*)d_in[11];  a.pb1 = (const float*)d_in[12];
  a.pw2 = (const float*)d_in[13];  a.pb2 = (const float*)d_in[14];
  a.gwih = (const float*)d_in[15]; a.gwhh = (const float*)d_in[16];
  a.gbih = (const float*)d_in[17]; a.gbhh = (const float*)d_in[18];
  a.cvw = (const float*)d_in[19];  a.cvb = (const float*)d_in[20];
  a.lsaL = (const float*)d_in[21]; a.lsaW = (const float*)d_in[22];
  a.lsaWb = (const float*)d_in[23]; a.lsav = (const float*)d_in[24];
  a.riw = (const float*)d_in[25];  a.rib = (const float*)d_in[26];
  a.l1wih = (const float*)d_in[27]; a.l1whh = (const float*)d_in[28];
  a.l1bih = (const float*)d_in[29]; a.l1bhh = (const float*)d_in[30];
  a.l2wih = (const float*)d_in[31]; a.l2whh = (const float*)d_in[32];
  a.l2bih = (const float*)d_in[33]; a.l2bhh = (const float*)d_in[34];
  a.melw = (const float*)d_in[35]; a.stopw = (const float*)d_in[36];
  a.stopb = (const float*)d_in[37];

  float* out = (float*)d_out;
  a.o_mels   = out;
  a.o_scores = out + 20480;
  a.o_attn   = out + 122880;
  a.o_h1     = out + 155648;
  a.o_h2     = out + 417792;
  a.o_c1     = out + 679936;
  a.o_c2     = out + 942080;
  a.o_ctx    = out + 1204224;
  a.o_stop   = out + 1335296;
  a.o_cum    = out + 1335552;

  float* ws = (float*)d_ws;
  a.ws_u    = ws;                    // 256*400
  a.ws_part = ws + 102400;           // 2*256*512
  a.ws_x    = ws + 364544;           // 256*1024
  a.ws_x2   = ws + 626688;           // 256*1024
  a.ws_g4   = ws + 888832;           // 4*256*4096

  dim3 blk(256);

  // 1. fused head + attention scores
  attn_fused_kernel<<<dim3(2, B_), blk, 0, stream>>>(a);
  // 2. softmax + context partials (TCH=2)
  ctx_smax_part_kernel<<<dim3(TCH, B_), blk, 0, stream>>>(a);
  // 3. rnn_in = [ctx | attn_hidden] @ riw^T + rib (ctx summed in staging)
  gemm_bf16<<<dim3(16, 4, 1), blk, 0, stream>>>(
      a.ws_part, a.ws_part + (size_t)B_ * INP, a.o_ctx, 512,
      a.riw, 640, 512,
      a.o_attn, 128, a.riw + 512, 640, 128,
      a.rib, nullptr, a.ws_x, 1024, 0, 0);
  // 4. LSTM1 gates (K-split partials)
  gemm_bf16<<<dim3(64, 4, 4), blk, 0, stream>>>(
      a.ws_x, nullptr, nullptr, 1024, a.l1wih, 1024, 1024,
      a.h1_0, 1024, a.l1whh, 1024, 1024,
      nullptr, nullptr, a.ws_g4, 4096, 0, 2);
  // 5. LSTM1 cell -> h1,c1 (d_out); x2 = x + h1
  lstm_cell_kernel<<<dim3(1024), blk, 0, stream>>>(
      a.ws_g4, a.l1bih, a.l1bhh, a.c1_0, a.ws_x, a.o_h1, a.o_c1, a.ws_x2);
  // 6. LSTM2 gates
  gemm_bf16<<<dim3(64, 4, 4), blk, 0, stream>>>(
      a.ws_x2, nullptr, nullptr, 1024, a.l2wih, 1024, 1024,
      a.h2_0, 1024, a.l2whh, 1024, 1024,
      nullptr, nullptr, a.ws_g4, 4096, 0, 2);
  // 7. fused cell2 + mel + stop
  mel_cell_kernel<<<dim3(4, B_), blk, 0, stream>>>(a);
}

// Round 16
// 256.749 us; speedup vs baseline: 1.2073x; 1.2073x over previous
//
#include <hip/hip_runtime.h>
#include <hip/hip_bf16.h>

#define B_ 256
#define T_ 400
#define NMELS 80
#define INP 512
#define DEC_ 128
#define LSTM_ 1024
#define FILT 32
#define KS 31
#define MAXR 20
#define TCH 2

typedef float f32x4 __attribute__((ext_vector_type(4)));
typedef short bf16x8 __attribute__((ext_vector_type(8)));

__device__ __forceinline__ short f2bf(float f) {
  union { float f; unsigned u; } v; v.f = f;
  unsigned u = v.u;
  unsigned r = (u + 0x7fffu + ((u >> 16) & 1u)) >> 16;
  return (short)r;
}

__device__ __forceinline__ bf16x8 pack8(float4 a0, float4 a1) {
  bf16x8 r;
  r[0] = f2bf(a0.x); r[1] = f2bf(a0.y); r[2] = f2bf(a0.z); r[3] = f2bf(a0.w);
  r[4] = f2bf(a1.x); r[5] = f2bf(a1.y); r[6] = f2bf(a1.z); r[7] = f2bf(a1.w);
  return r;
}

__device__ __forceinline__ float sigmoidf_(float x) {
  return 1.f / (1.f + __expf(-x));
}
__device__ __forceinline__ float tanhf_(float x) {
  float e = __expf(2.f * x);
  return 1.f - 2.f / (e + 1.f);
}

// ---------------------------------------------------------------------------
struct Args {
  const float *enc, *esp, *prein, *ah0, *h1_0, *h2_0, *c1_0, *c2_0, *ctx0, *cum;
  const int* chars;
  const float *pw1, *pb1, *pw2, *pb2;
  const float *gwih, *gwhh, *gbih, *gbhh;
  const float *cvw, *cvb, *lsaL, *lsaW, *lsaWb, *lsav;
  const float *riw, *rib;
  const float *l1wih, *l1whh, *l1bih, *l1bhh;
  const float *l2wih, *l2whh, *l2bih, *l2bhh;
  const float *melw, *stopw, *stopb;
  float *o_mels, *o_scores, *o_attn, *o_h1, *o_h2, *o_c1, *o_c2, *o_ctx, *o_stop, *o_cum;
  float *ws_pq, *ws_u, *ws_part, *ws_x, *ws_x2, *ws_g4;
};

// ---------------------------------------------------------------------------
// Fused head: prenet1 + prenet2 + gi + gh + GRU cell + processed_query.
// K-split dual accumulators on the long dots for 2x load ILP.
// ---------------------------------------------------------------------------
__global__ __launch_bounds__(256) void head_kernel(Args a) {
  __shared__ float s_x[768];    // [ctx | prenet_out]
  __shared__ float s_p[80];
  __shared__ float s_h1[256];
  __shared__ float s_hold[DEC_];
  __shared__ float s_gi[384];
  __shared__ float s_gh[384];
  __shared__ float s_h2[DEC_];
  const int b = blockIdx.x, tid = threadIdx.x;

  if (tid < 80)   s_p[tid]   = a.prein[(size_t)b * 80 + tid];
  if (tid < DEC_) s_hold[tid] = a.ah0[(size_t)b * DEC_ + tid];
  for (int i = tid; i < INP; i += 256) s_x[i] = a.ctx0[(size_t)b * INP + i];
  __syncthreads();

  // prenet1 (K=80)
  {
    const float* w = a.pw1 + (size_t)tid * 80;
    float acc = a.pb1[tid];
#pragma unroll
    for (int k = 0; k < 80; k += 4)
      acc += w[k] * s_p[k] + w[k+1] * s_p[k+1] + w[k+2] * s_p[k+2] + w[k+3] * s_p[k+3];
    s_h1[tid] = fmaxf(acc, 0.f);
  }
  __syncthreads();

  // prenet2 (K=256), 2 k-half accumulators
  {
    const float4* w = (const float4*)(a.pw2 + (size_t)tid * 256);
    float a0 = a.pb2[tid], a1 = 0.f;
#pragma unroll 8
    for (int q = 0; q < 32; ++q) {
      float4 w0 = w[q], w1 = w[32 + q];
      a0 += w0.x * s_h1[q*4]       + w0.y * s_h1[q*4+1]       + w0.z * s_h1[q*4+2]       + w0.w * s_h1[q*4+3];
      a1 += w1.x * s_h1[128 + q*4] + w1.y * s_h1[128 + q*4+1] + w1.z * s_h1[128 + q*4+2] + w1.w * s_h1[128 + q*4+3];
    }
    s_x[INP + tid] = fmaxf(a0 + a1, 0.f);
  }
  __syncthreads();

  // gi (K=768), 2 k-half accumulators
  for (int n = tid; n < 384; n += 256) {
    const float4* w = (const float4*)(a.gwih + (size_t)n * 768);
    float a0 = a.gbih[n], a1 = 0.f;
#pragma unroll 8
    for (int q = 0; q < 96; ++q) {
      float4 w0 = w[q], w1 = w[96 + q];
      a0 += w0.x * s_x[q*4]       + w0.y * s_x[q*4+1]       + w0.z * s_x[q*4+2]       + w0.w * s_x[q*4+3];
      a1 += w1.x * s_x[384 + q*4] + w1.y * s_x[384 + q*4+1] + w1.z * s_x[384 + q*4+2] + w1.w * s_x[384 + q*4+3];
    }
    s_gi[n] = a0 + a1;
  }
  // gh (K=128)
  for (int n = tid; n < 384; n += 256) {
    const float4* w = (const float4*)(a.gwhh + (size_t)n * DEC_);
    float acc = a.gbhh[n];
#pragma unroll
    for (int q = 0; q < 32; ++q) {
      float4 wv = w[q];
      acc += wv.x * s_hold[q*4] + wv.y * s_hold[q*4+1] + wv.z * s_hold[q*4+2] + wv.w * s_hold[q*4+3];
    }
    s_gh[n] = acc;
  }
  __syncthreads();

  if (tid < DEC_) {
    float r = sigmoidf_(s_gi[tid] + s_gh[tid]);
    float z = sigmoidf_(s_gi[128 + tid] + s_gh[128 + tid]);
    float n = tanhf_(s_gi[256 + tid] + r * s_gh[256 + tid]);
    float h = (1.f - z) * n + z * s_hold[tid];
    s_h2[tid] = h;
    a.o_attn[(size_t)b * DEC_ + tid] = h;
  }
  __syncthreads();

  if (tid < DEC_) {
    const float4* w = (const float4*)(a.lsaW + (size_t)tid * DEC_);
    float acc = a.lsaWb[tid];
#pragma unroll
    for (int q = 0; q < 32; ++q) {
      float4 wv = w[q];
      acc += wv.x * s_h2[q*4] + wv.y * s_h2[q*4+1] + wv.z * s_h2[q*4+2] + wv.w * s_h2[q*4+3];
    }
    a.ws_pq[(size_t)b * DEC_ + tid] = acc;
  }
}

// ---------------------------------------------------------------------------
// Attention scores, thread-per-t (VALU). Block (half, b): 200 t's, one per
// thread. esp read as sequential float4 per thread; s_L broadcast from LDS.
// ---------------------------------------------------------------------------
__global__ __launch_bounds__(256) void attn_score_kernel(Args a) {
  __shared__ float s_cum[232];
  __shared__ float s_w[FILT * KS];
  __shared__ float s_cb[FILT];
  __shared__ float s_L[DEC_ * FILT];
  __shared__ float s_pq[DEC_];
  __shared__ float s_v[DEC_];

  const int half = blockIdx.x;
  const int b    = blockIdx.y;
  const int tid  = threadIdx.x;
  const int t0   = half * 200;

  for (int i = tid; i < 230; i += 256) {
    int t = t0 - 15 + i;
    s_cum[i] = (t >= 0 && t < T_) ? a.cum[(size_t)b * T_ + t] : 0.f;
  }
  for (int i = tid; i < FILT * KS; i += 256) s_w[i] = a.cvw[i];
  for (int i = tid; i < DEC_ * FILT; i += 256) s_L[i] = a.lsaL[i];
  if (tid < FILT) s_cb[tid] = a.cvb[tid];
  if (tid < DEC_) { s_pq[tid] = a.ws_pq[(size_t)b * DEC_ + tid]; s_v[tid] = a.lsav[tid]; }
  __syncthreads();

  if (tid >= 200) return;
  const int t = t0 + tid;

  // conv31 for this t
  float cf[FILT];
  {
    float c[KS];
#pragma unroll
    for (int k = 0; k < KS; ++k) c[k] = s_cum[tid + k];
#pragma unroll
    for (int f = 0; f < FILT; ++f) {
      float acc = s_cb[f];
#pragma unroll
      for (int k = 0; k < KS; ++k) acc += c[k] * s_w[f * KS + k];
      cf[f] = acc;
    }
  }

  // u = sum_d tanh(pq[d] + esp[t][d] + PL[d]) * v[d], 2 accumulator streams
  const float4* e4 = (const float4*)(a.esp + ((size_t)b * T_ + t) * DEC_);
  float u0 = 0.f, u1 = 0.f;
  for (int d4 = 0; d4 < DEC_ / 4; d4 += 2) {
    float4 e0 = e4[d4];
    float4 e1 = e4[d4 + 1];
    const float ev0[4] = {e0.x, e0.y, e0.z, e0.w};
    const float ev1[4] = {e1.x, e1.y, e1.z, e1.w};
#pragma unroll
    for (int c = 0; c < 4; ++c) {
      int d = d4 * 4 + c;
      float pl = 0.f;
      const float* ld = &s_L[d * FILT];
#pragma unroll
      for (int f = 0; f < FILT; ++f) pl += cf[f] * ld[f];
      u0 += tanhf_(s_pq[d] + ev0[c] + pl) * s_v[d];
    }
#pragma unroll
    for (int c = 0; c < 4; ++c) {
      int d = (d4 + 1) * 4 + c;
      float pl = 0.f;
      const float* ld = &s_L[d * FILT];
#pragma unroll
      for (int f = 0; f < FILT; ++f) pl += cf[f] * ld[f];
      u1 += tanhf_(s_pq[d] + ev1[c] + pl) * s_v[d];
    }
  }
  float u = u0 + u1;
  if (a.chars[(size_t)b * T_ + t] == 0) u = 0.f;
  a.ws_u[(size_t)b * T_ + t] = u;
}

// ---------------------------------------------------------------------------
// Softmax (redundant per tc) + context partial over 200-t chunk. Block (tc,b).
// ---------------------------------------------------------------------------
__global__ __launch_bounds__(256) void ctx_smax_part_kernel(Args a) {
  __shared__ float s_u[T_];
  __shared__ float s_red[8];
  const int tc = blockIdx.x, b = blockIdx.y, tid = threadIdx.x;
  const int lane = tid & 63, wave = tid >> 6;

  float mx = -1e30f;
  for (int t = tid; t < T_; t += 256) {
    float v = a.ws_u[(size_t)b * T_ + t];
    s_u[t] = v;
    mx = fmaxf(mx, v);
  }
#pragma unroll
  for (int o = 32; o >= 1; o >>= 1) mx = fmaxf(mx, __shfl_xor(mx, o));
  if (lane == 0) s_red[wave] = mx;
  __syncthreads();
  mx = fmaxf(fmaxf(s_red[0], s_red[1]), fmaxf(s_red[2], s_red[3]));

  float smv = 0.f;
  for (int t = tid; t < T_; t += 256) {
    float e = __expf(s_u[t] - mx);
    s_u[t] = e;
    smv += e;
  }
#pragma unroll
  for (int o = 32; o >= 1; o >>= 1) smv += __shfl_xor(smv, o);
  if (lane == 0) s_red[4 + wave] = smv;
  __syncthreads();
  smv = s_red[4] + s_red[5] + s_red[6] + s_red[7];
  float inv = 1.f / smv;
  for (int t = tid; t < T_; t += 256) {
    float s = s_u[t] * inv;
    s_u[t] = s;
    if (tc == 0) {
      a.o_scores[(size_t)b * T_ + t] = s;
      a.o_cum[(size_t)b * T_ + t] = a.cum[(size_t)b * T_ + t] + s;
    }
  }
  __syncthreads();

  const int start = tc * 200;
  const float2* Eb = (const float2*)(a.enc + ((size_t)b * T_ + start) * INP) + tid;
  const float* su = &s_u[start];
  float2 a0 = {0.f, 0.f}, a1 = {0.f, 0.f}, a2 = {0.f, 0.f}, a3 = {0.f, 0.f};
  for (int t = 0; t < 200; t += 4) {
    float s0 = su[t], s1 = su[t + 1], s2 = su[t + 2], s3 = su[t + 3];
    float2 e0 = Eb[(size_t)(t)     * 256];
    float2 e1 = Eb[(size_t)(t + 1) * 256];
    float2 e2 = Eb[(size_t)(t + 2) * 256];
    float2 e3 = Eb[(size_t)(t + 3) * 256];
    a0.x += s0 * e0.x; a0.y += s0 * e0.y;
    a1.x += s1 * e1.x; a1.y += s1 * e1.y;
    a2.x += s2 * e2.x; a2.y += s2 * e2.y;
    a3.x += s3 * e3.x; a3.y += s3 * e3.y;
  }
  float2 r;
  r.x = (a0.x + a1.x) + (a2.x + a3.x);
  r.y = (a0.y + a1.y) + (a2.y + a3.y);
  *(float2*)&a.ws_part[((size_t)tc * B_ + b) * INP + 2 * tid] = r;
}

// ---------------------------------------------------------------------------
// Generic bf16-MFMA GEMM + optional A1-partial-sum staging (proven).
// ---------------------------------------------------------------------------
__global__ __launch_bounds__(256) void gemm_bf16(
    const float* __restrict__ A1, const float* __restrict__ A1b,
    float* __restrict__ ctx_side, int lda1,
    const float* __restrict__ W1, int ldw1, int K1,
    const float* __restrict__ A2, int lda2, const float* __restrict__ W2, int ldw2, int K2,
    const float* __restrict__ bias1, const float* __restrict__ bias2,
    float* __restrict__ out, int ldo, int act, int zmode)
{
  __shared__ __align__(16) short sA[64][40];
  __shared__ __align__(16) short sB[64][40];
  const int tid  = threadIdx.x;
  const int lane = tid & 63;
  const int wave = tid >> 6;
  const int wr = (wave >> 1) * 32;
  const int wc = (wave & 1) * 32;
  const int bm = blockIdx.y * 64;
  const int bn = blockIdx.x * 64;
  const int sr = tid >> 2;
  const int sk = (tid & 3) * 8;
  const int l15 = lane & 15;
  const int kq  = (lane >> 4) * 8;

  int kb1 = 0, ke1 = K1, kb2 = 0, ke2 = K2;
  if (zmode == 2) {
    int p = blockIdx.z >> 1, h = blockIdx.z & 1;
    if (p == 0) { ke2 = 0; int half = K1 >> 1; kb1 = h * half; ke1 = kb1 + half; }
    else        { ke1 = 0; int half = K2 >> 1; kb2 = h * half; ke2 = kb2 + half; }
  }
  float* outp = out;
  if (zmode == 2) outp += (size_t)blockIdx.z * (size_t)(gridDim.y * 64) * ldo;

  f32x4 acc[2][2];
#pragma unroll
  for (int i = 0; i < 2; ++i)
#pragma unroll
    for (int j = 0; j < 2; ++j) acc[i][j] = (f32x4){0.f, 0.f, 0.f, 0.f};

  for (int pair = 0; pair < 2; ++pair) {
    const int kb = pair ? kb2 : kb1;
    const int ke = pair ? ke2 : ke1;
    if (ke <= kb) continue;
    const float* A = pair ? A2 : A1;
    const float* Ab = pair ? nullptr : A1b;
    const float* W = pair ? W2 : W1;
    const int lda = pair ? lda2 : lda1;
    const int ldw = pair ? ldw2 : ldw1;
    const float* arow  = A + (size_t)(bm + sr) * lda;
    const float* arowb = Ab ? Ab + (size_t)(bm + sr) * lda : nullptr;
    const float* wrow  = W + (size_t)(bn + sr) * ldw;
    float* crow = (pair == 0 && ctx_side) ? ctx_side + (size_t)(bm + sr) * lda : nullptr;

    float4 ra0, ra1, rb0, rb1;
    if (kb + 32 <= ke) {
      const float* pa = arow + kb + sk;
      const float* pw = wrow + kb + sk;
      ra0 = *(const float4*)pa; ra1 = *(const float4*)(pa + 4);
      if (arowb) {
        const float* pb = arowb + kb + sk;
        float4 b0 = *(const float4*)pb, b1 = *(const float4*)(pb + 4);
        ra0.x += b0.x; ra0.y += b0.y; ra0.z += b0.z; ra0.w += b0.w;
        ra1.x += b1.x; ra1.y += b1.y; ra1.z += b1.z; ra1.w += b1.w;
      }
      rb0 = *(const float4*)pw; rb1 = *(const float4*)(pw + 4);
    }
    for (int k0 = kb; k0 < ke; k0 += 32) {
      __syncthreads();
      if (k0 + 32 <= ke) {
        *(bf16x8*)&sA[sr][sk] = pack8(ra0, ra1);
        *(bf16x8*)&sB[sr][sk] = pack8(rb0, rb1);
        if (crow) {
          *(float4*)(crow + k0 + sk) = ra0;
          *(float4*)(crow + k0 + sk + 4) = ra1;
        }
        if (k0 + 64 <= ke) {
          const float* pa = arow + k0 + 32 + sk;
          const float* pw = wrow + k0 + 32 + sk;
          ra0 = *(const float4*)pa; ra1 = *(const float4*)(pa + 4);
          if (arowb) {
            const float* pb = arowb + k0 + 32 + sk;
            float4 b0 = *(const float4*)pb, b1 = *(const float4*)(pb + 4);
            ra0.x += b0.x; ra0.y += b0.y; ra0.z += b0.z; ra0.w += b0.w;
            ra1.x += b1.x; ra1.y += b1.y; ra1.z += b1.z; ra1.w += b1.w;
          }
          rb0 = *(const float4*)pw; rb1 = *(const float4*)(pw + 4);
        }
      } else {
        short* da = &sA[sr][sk];
        short* db = &sB[sr][sk];
#pragma unroll
        for (int j = 0; j < 8; ++j) {
          int k = k0 + sk + j;
          float av = (k < ke) ? arow[k] + (arowb ? arowb[k] : 0.f) : 0.f;
          da[j] = (k < ke) ? f2bf(av) : (short)0;
          db[j] = (k < ke) ? f2bf(wrow[k]) : (short)0;
        }
      }
      __syncthreads();
      bf16x8 af[2], bfv[2];
      af[0]  = *(const bf16x8*)&sA[wr + l15][kq];
      af[1]  = *(const bf16x8*)&sA[wr + 16 + l15][kq];
      bfv[0] = *(const bf16x8*)&sB[wc + l15][kq];
      bfv[1] = *(const bf16x8*)&sB[wc + 16 + l15][kq];
#pragma unroll
      for (int i = 0; i < 2; ++i)
#pragma unroll
        for (int j = 0; j < 2; ++j)
          acc[i][j] = __builtin_amdgcn_mfma_f32_16x16x32_bf16(af[i], bfv[j], acc[i][j], 0, 0, 0);
    }
  }

#pragma unroll
  for (int i = 0; i < 2; ++i) {
#pragma unroll
    for (int j = 0; j < 2; ++j) {
      int n = bn + wc + j * 16 + l15;
      float bv = 0.f;
      if (zmode == 0) bv = (bias1 ? bias1[n] : 0.f) + (bias2 ? bias2[n] : 0.f);
#pragma unroll
      for (int r = 0; r < 4; ++r) {
        int m = bm + wr + i * 16 + (lane >> 4) * 4 + r;
        float v = acc[i][j][r] + bv;
        if (act == 1) v = fmaxf(v, 0.f);
        outp[(size_t)m * ldo + n] = v;
      }
    }
  }
}

// ---------------------------------------------------------------------------
// LSTM cell (4 gate partials) + residual (proven).
// ---------------------------------------------------------------------------
__global__ __launch_bounds__(256) void lstm_cell_kernel(
    const float* __restrict__ g4, const float* __restrict__ bih,
    const float* __restrict__ bhh, const float* __restrict__ c_old,
    const float* __restrict__ x_in,
    float* __restrict__ h_out, float* __restrict__ c_out,
    float* __restrict__ x_out)
{
  const size_t SEG = (size_t)B_ * 4096;
  int idx = blockIdx.x * 256 + threadIdx.x;
  if (idx >= B_ * LSTM_) return;
  int b = idx >> 10, j = idx & 1023;
  const float* gb = g4 + (size_t)b * 4096;
  float ig = gb[j]        + gb[SEG + j]        + gb[2*SEG + j]        + gb[3*SEG + j]        + bih[j]        + bhh[j];
  float fg = gb[1024 + j] + gb[SEG + 1024 + j] + gb[2*SEG + 1024 + j] + gb[3*SEG + 1024 + j] + bih[1024 + j] + bhh[1024 + j];
  float gg = gb[2048 + j] + gb[SEG + 2048 + j] + gb[2*SEG + 2048 + j] + gb[3*SEG + 2048 + j] + bih[2048 + j] + bhh[2048 + j];
  float og = gb[3072 + j] + gb[SEG + 3072 + j] + gb[2*SEG + 3072 + j] + gb[3*SEG + 3072 + j] + bih[3072 + j] + bhh[3072 + j];
  float cn = sigmoidf_(fg) * c_old[idx] + sigmoidf_(ig) * tanhf_(gg);
  float hn = sigmoidf_(og) * tanhf_(cn);
  h_out[idx] = hn;
  c_out[idx] = cn;
  x_out[idx] = x_in[idx] + hn;
}

// ---------------------------------------------------------------------------
// mel + stop head (R14-proven). Block (part, b): 20 mel rows, 5/wave.
// ---------------------------------------------------------------------------
__global__ __launch_bounds__(256) void mel_stop_kernel(Args a) {
  __shared__ float s_x[LSTM_];
  __shared__ float s_c[INP];
  __shared__ float s_red[4];
  const int part = blockIdx.x;       // 0..3
  const int b    = blockIdx.y;
  const int tid  = threadIdx.x;
  const int lane = tid & 63, wave = tid >> 6;

  for (int k = tid * 4; k < LSTM_; k += 1024)
    *(float4*)&s_x[k] = *(const float4*)&a.ws_x[(size_t)b * LSTM_ + k];
  if (part == 0)
    for (int k = tid; k < INP; k += 256) s_c[k] = a.o_ctx[(size_t)b * INP + k];
  __syncthreads();

  const int n0 = part * 20 + wave * 5;
  const float* w0 = a.melw + (size_t)(n0)     * MAXR * LSTM_;
  const float* w1 = a.melw + (size_t)(n0 + 1) * MAXR * LSTM_;
  const float* w2 = a.melw + (size_t)(n0 + 2) * MAXR * LSTM_;
  const float* w3 = a.melw + (size_t)(n0 + 3) * MAXR * LSTM_;
  const float* w4 = a.melw + (size_t)(n0 + 4) * MAXR * LSTM_;
  float ac0 = 0.f, ac1 = 0.f, ac2 = 0.f, ac3 = 0.f, ac4 = 0.f;
#pragma unroll
  for (int j = 0; j < 4; ++j) {
    int k = j * 256 + lane * 4;
    float4 xv = *(const float4*)&s_x[k];
    float4 v0 = *(const float4*)(w0 + k);
    float4 v1 = *(const float4*)(w1 + k);
    float4 v2 = *(const float4*)(w2 + k);
    float4 v3 = *(const float4*)(w3 + k);
    float4 v4 = *(const float4*)(w4 + k);
    ac0 += v0.x * xv.x + v0.y * xv.y + v0.z * xv.z + v0.w * xv.w;
    ac1 += v1.x * xv.x + v1.y * xv.y + v1.z * xv.z + v1.w * xv.w;
    ac2 += v2.x * xv.x + v2.y * xv.y + v2.z * xv.z + v2.w * xv.w;
    ac3 += v3.x * xv.x + v3.y * xv.y + v3.z * xv.z + v3.w * xv.w;
    ac4 += v4.x * xv.x + v4.y * xv.y + v4.z * xv.z + v4.w * xv.w;
  }
#pragma unroll
  for (int o = 32; o >= 1; o >>= 1) {
    ac0 += __shfl_xor(ac0, o);
    ac1 += __shfl_xor(ac1, o);
    ac2 += __shfl_xor(ac2, o);
    ac3 += __shfl_xor(ac3, o);
    ac4 += __shfl_xor(ac4, o);
  }
  if (lane == 0) {
    float* om = a.o_mels + (size_t)b * NMELS + n0;
    om[0] = ac0; om[1] = ac1; om[2] = ac2; om[3] = ac3; om[4] = ac4;
  }

  if (part == 0) {
    float p = 0.f;
    for (int k = tid; k < LSTM_; k += 256) p += s_x[k] * a.stopw[k];
    for (int k = tid; k < INP; k += 256) p += s_c[k] * a.stopw[LSTM_ + k];
#pragma unroll
    for (int o = 32; o >= 1; o >>= 1) p += __shfl_xor(p, o);
    if (lane == 0) s_red[wave] = p;
    __syncthreads();
    if (tid == 0) {
      float t = s_red[0] + s_red[1] + s_red[2] + s_red[3] + a.stopb[0];
      a.o_stop[b] = sigmoidf_(t);
    }
  }
}

// ---------------------------------------------------------------------------
extern "C" void kernel_launch(void* const* d_in, const int* in_sizes, int n_in,
                              void* d_out, int out_size, void* d_ws, size_t ws_size,
                              hipStream_t stream) {
  Args a;
  a.enc   = (const float*)d_in[0];
  a.esp   = (const float*)d_in[1];
  a.prein = (const float*)d_in[2];
  a.ah0   = (const float*)d_in[3];
  a.h1_0  = (const float*)d_in[4];
  a.h2_0  = (const float*)d_in[5];
  a.c1_0  = (const float*)d_in[6];
  a.c2_0  = (const float*)d_in[7];
  a.ctx0  = (const float*)d_in[8];
  a.cum   = (const float*)d_in[9];
  a.chars = (const int*)d_in[10];
  a.pw1 = (const float*)d_in[11];  a.pb1 = (const float*)d_in[12];
  a.pw2 = (const float*)d_in[13];  a.pb2 = (const float*)d_in[14];
  a.gwih = (const float*)d_in[15]; a.gwhh = (const float*)d_in[16];
  a.gbih = (const float*)d_in[17]; a.gbhh = (const float*)d_in[18];
  a.cvw = (const float*)d_in[19];  a.cvb = (const float*)d_in[20];
  a.lsaL = (const float*)d_in[21]; a.lsaW = (const float*)d_in[22];
  a.lsaWb = (const float*)d_in[23]; a.lsav = (const float*)d_in[24];
  a.riw = (const float*)d_in[25];  a.rib = (const float*)d_in[26];
  a.l1wih = (const float*)d_in[27]; a.l1whh = (const float*)d_in[28];
  a.l1bih = (const float*)d_in[29]; a.l1bhh = (const float*)d_in[30];
  a.l2wih = (const float*)d_in[31]; a.l2whh = (const float*)d_in[32];
  a.l2bih = (const float*)d_in[33]; a.l2bhh = (const float*)d_in[34];
  a.melw = (const float*)d_in[35]; a.stopw = (const float*)d_in[36];
  a.stopb = (const float*)d_in[37];

  float* out = (float*)d_out;
  a.o_mels   = out;
  a.o_scores = out + 20480;
  a.o_attn   = out + 122880;
  a.o_h1     = out + 155648;
  a.o_h2     = out + 417792;
  a.o_c1     = out + 679936;
  a.o_c2     = out + 942080;
  a.o_ctx    = out + 1204224;
  a.o_stop   = out + 1335296;
  a.o_cum    = out + 1335552;

  float* ws = (float*)d_ws;
  a.ws_pq   = ws;                    // 256*128
  a.ws_u    = ws + 32768;            // 256*400
  a.ws_part = ws + 135168;           // 2*256*512
  a.ws_x    = ws + 397312;           // 256*1024 (x, later reused as x3)
  a.ws_x2   = ws + 659456;           // 256*1024
  a.ws_g4   = ws + 921600;           // 4*256*4096

  dim3 blk(256);

  // 1. fused head
  head_kernel<<<dim3(B_), blk, 0, stream>>>(a);
  // 2. attention scores (thread-per-t VALU)
  attn_score_kernel<<<dim3(2, B_), blk, 0, stream>>>(a);
  // 3. softmax + context partials (TCH=2)
  ctx_smax_part_kernel<<<dim3(TCH, B_), blk, 0, stream>>>(a);
  // 4. rnn_in = [ctx | attn_hidden] @ riw^T + rib (ctx summed in staging)
  gemm_bf16<<<dim3(16, 4, 1), blk, 0, stream>>>(
      a.ws_part, a.ws_part + (size_t)B_ * INP, a.o_ctx, 512,
      a.riw, 640, 512,
      a.o_attn, 128, a.riw + 512, 640, 128,
      a.rib, nullptr, a.ws_x, 1024, 0, 0);
  // 5. LSTM1 gates (K-split partials)
  gemm_bf16<<<dim3(64, 4, 4), blk, 0, stream>>>(
      a.ws_x, nullptr, nullptr, 1024, a.l1wih, 1024, 1024,
      a.h1_0, 1024, a.l1whh, 1024, 1024,
      nullptr, nullptr, a.ws_g4, 4096, 0, 2);
  // 6. LSTM1 cell -> h1,c1 (d_out); x2 = x + h1
  lstm_cell_kernel<<<dim3(1024), blk, 0, stream>>>(
      a.ws_g4, a.l1bih, a.l1bhh, a.c1_0, a.ws_x, a.o_h1, a.o_c1, a.ws_x2);
  // 7. LSTM2 gates
  gemm_bf16<<<dim3(64, 4, 4), blk, 0, stream>>>(
      a.ws_x2, nullptr, nullptr, 1024, a.l2wih, 1024, 1024,
      a.h2_0, 1024, a.l2whh, 1024, 1024,
      nullptr, nullptr, a.ws_g4, 4096, 0, 2);
  // 8. LSTM2 cell -> h2,c2 (d_out); x3 = x2 + h2 (into recycled ws_x)
  lstm_cell_kernel<<<dim3(1024), blk, 0, stream>>>(
      a.ws_g4, a.l2bih, a.l2bhh, a.c2_0, a.ws_x2, a.o_h2, a.o_c2, a.ws_x);
  // 9. mel + stop heads (4 blocks per row)
  mel_stop_kernel<<<dim3(4, B_), blk, 0, stream>>>(a);
}